// Round 1
// 184.367 us; speedup vs baseline: 1.1206x; 1.1206x over previous
//
#include <hip/hip_runtime.h>
#include <hip/hip_bf16.h>

// QJL with orthogonal projections, MI355X (gfx950).
// out[t] = scale * sum_m sign(K[t]·S[m]) * (Q[t]·S[m]),  t in [0,131072)
//
// R7 structure (fused K/Q passes):
//  - 4096 wgs x 256 thr, one 32-token tile each.
//  - prep kernel: S -> bf16 hi/lo tables in d_ws, PRE-SWIZZLED into MFMA
//    A-fragment order (per (wave,ks,ms): 64 lanes x 16 B contiguous) so the
//    main loop's S loads are single coalesced dwordx4 from L2.
//  - SINGLE fused k-loop: per ks, load ah/al once and feed FOUR MFMA chains:
//    accC += ah·bk + al·bk + ah·bl   (3-pass sign dot, proven in R5/R6)
//    accQ += ah·bq                    (Q projection)
//    This removes loop2's separate S reload (16 of 48 S loads/wave) and
//    halves the number of L2-load wait points per wave (8 -> 4).
//  - Epilogue: s = sign(accC) with |C| < TAU resolved by the proven
//    OpenBLAS-chain arbiter (sequential ascending fp32 FMA, now with
//    float4 loads — FMA order unchanged, np.sign(0)=0). part += s*qp
//    directly; no negw/zerow masks needed anymore.
//  - Wave butterfly + LDS cross-wave combine, one store per token.

#define DIM        128
#define NPROJ      256
#define TILE_T     32
#define NWG        4096        // NTOK / TILE_T
#define LDS_STRIDE 136         // bf16 elems; m97-proven padded layout
#define TAU        6.0e-3f
#define SCALE      0.0048957583489668f  // sqrt(pi/2)/256

typedef __attribute__((ext_vector_type(8))) short short8;  // 8 bf16 = 4 VGPRs
typedef __attribute__((ext_vector_type(4))) float f32x4;

static __device__ __forceinline__ unsigned short bf16_rne(float x){
    unsigned int u = __builtin_bit_cast(unsigned int, x);
    u += 0x7FFFu + ((u >> 16) & 1u);
    return (unsigned short)(u >> 16);
}

// Reference-exact sign: OpenBLAS sgemm per-element k-chain, fp32 FMA,
// ascending d. Returns np.sign(dot) in {-1, 0, +1}.  [verified round 5]
// R7: float4 loads (4x fewer load instrs); the FMA chain order is untouched.
static __device__ __attribute__((noinline))
float ref_sign(const float* __restrict__ Kg, const float* __restrict__ S,
               int tok, int m){
    const float4* kr = (const float4*)(Kg + (size_t)tok * DIM);
    const float4* sr = (const float4*)(S  + (size_t)m   * DIM);
    float acc = 0.f;
#pragma unroll 4
    for (int d = 0; d < DIM/4; ++d){
        float4 k4 = kr[d];
        float4 s4 = sr[d];
        acc = __builtin_fmaf(k4.x, s4.x, acc);
        acc = __builtin_fmaf(k4.y, s4.y, acc);
        acc = __builtin_fmaf(k4.z, s4.z, acc);
        acc = __builtin_fmaf(k4.w, s4.w, acc);
    }
    return (acc > 0.f) ? 1.f : ((acc < 0.f) ? -1.f : 0.f);
}

// S -> bf16 hi/lo, swizzled to fragment order:
//   tab[(((g*4+ks)*4+ms)*64 + lane)*8 + e] = conv(S[g*64+ms*16+(lane&15)]
//                                                  [ks*32+(lane>>4)*8+e])
__global__ void prep_s_kernel(const float* __restrict__ S,
                              unsigned short* __restrict__ shi,
                              unsigned short* __restrict__ slo){
    int t    = blockIdx.x * 256 + threadIdx.x;   // 4096 threads
    int lane = t & 63;
    int ms   = (t >> 6) & 3;
    int ks   = (t >> 8) & 3;
    int g    = (t >> 10) & 3;
    int m    = g*64 + ms*16 + (lane & 15);
    int d    = ks*32 + (lane >> 4)*8;
    const float4* p = (const float4*)(S + (size_t)m*DIM + d);
    float4 x0 = p[0], x1 = p[1];
    float xs[8] = {x0.x,x0.y,x0.z,x0.w, x1.x,x1.y,x1.z,x1.w};
    size_t base = ((size_t)t) * 8;
    unsigned long long h0=0,h1=0,l0=0,l1=0;
#pragma unroll
    for (int e = 0; e < 4; ++e){
        unsigned short hb = bf16_rne(xs[e]);
        float hf = __builtin_bit_cast(float, (unsigned int)hb << 16);
        h0 |= (unsigned long long)hb                    << (16*e);
        l0 |= (unsigned long long)bf16_rne(xs[e] - hf)  << (16*e);
    }
#pragma unroll
    for (int e = 0; e < 4; ++e){
        unsigned short hb = bf16_rne(xs[4+e]);
        float hf = __builtin_bit_cast(float, (unsigned int)hb << 16);
        h1 |= (unsigned long long)hb                      << (16*e);
        l1 |= (unsigned long long)bf16_rne(xs[4+e] - hf)  << (16*e);
    }
    *(unsigned long long*)(shi + base)     = h0;
    *(unsigned long long*)(shi + base + 4) = h1;
    *(unsigned long long*)(slo + base)     = l0;
    *(unsigned long long*)(slo + base + 4) = l1;
}

// Load this wave's A-fragments for one ks: table path (coalesced 16B/lane)
// or inline-convert fallback from fp32 S. Always loads hi AND lo (fused loop
// needs both every ks).
template<bool USE_TAB>
static __device__ __forceinline__
void load_afrags(const unsigned short* __restrict__ shi_tab,
                 const unsigned short* __restrict__ slo_tab,
                 const float* __restrict__ S,
                 int wave, int ks, int l16, int quad, int lane,
                 short8 ah[4], short8 al[4]){
    if (USE_TAB){
#pragma unroll
        for (int ms = 0; ms < 4; ++ms){
            size_t off = ((size_t)((wave*4 + ks)*4 + ms)*64 + lane)*8;
            ah[ms] = *(const short8*)(shi_tab + off);
            al[ms] = *(const short8*)(slo_tab + off);
        }
    } else {
#pragma unroll
        for (int ms = 0; ms < 4; ++ms){
            const float4* p = (const float4*)(S + (size_t)(wave*64 + ms*16 + l16)*DIM
                                              + ks*32 + quad*8);
            float4 x0 = p[0], x1 = p[1];
            float xs[8] = {x0.x,x0.y,x0.z,x0.w, x1.x,x1.y,x1.z,x1.w};
            short8 h, l;
#pragma unroll
            for (int e = 0; e < 8; ++e){
                unsigned short hb = bf16_rne(xs[e]);
                float hf = __builtin_bit_cast(float, (unsigned int)hb << 16);
                h[e] = (short)hb;
                l[e] = (short)bf16_rne(xs[e] - hf);
            }
            ah[ms] = h;
            al[ms] = l;
        }
    }
}

template<bool USE_TAB>
__global__ __launch_bounds__(256, 4)
void qjl_kernel(const float* __restrict__ Qg, const float* __restrict__ Kg,
                const float* __restrict__ S,
                const unsigned short* __restrict__ shi_tab,
                const unsigned short* __restrict__ slo_tab,
                float* __restrict__ out)
{
    __shared__ unsigned short khi[TILE_T * LDS_STRIDE];
    __shared__ unsigned short klo[TILE_T * LDS_STRIDE];
    __shared__ unsigned short qhi[TILE_T * LDS_STRIDE];
    __shared__ float red[4][TILE_T];

    const int tid  = threadIdx.x;
    const int wave = tid >> 6;
    const int lane = tid & 63;
    const int l16  = lane & 15;
    const int quad = lane >> 4;
    const int tok0 = blockIdx.x * TILE_T;

    // ---- stage: 32 tokens of K and Q, fp32 -> bf16 hi/lo in LDS ----
    {
        const float4* ksrc = (const float4*)(Kg + (size_t)tok0 * DIM);
        const float4* qsrc = (const float4*)(Qg + (size_t)tok0 * DIM);
        float4 kv[4], qv[4];
#pragma unroll
        for (int j = 0; j < 4; ++j){ kv[j] = ksrc[tid + j*256]; qv[j] = qsrc[tid + j*256]; }
#pragma unroll
        for (int j = 0; j < 4; ++j){
            int i   = tid + j*256;
            int row = i >> 5;
            int c   = i & 31;
            float kx[4] = {kv[j].x, kv[j].y, kv[j].z, kv[j].w};
            float qx[4] = {qv[j].x, qv[j].y, qv[j].z, qv[j].w};
            unsigned long long hp = 0, lp = 0, qp = 0;
#pragma unroll
            for (int e = 0; e < 4; ++e){
                unsigned short hb = bf16_rne(kx[e]);
                float hf = __builtin_bit_cast(float, (unsigned int)hb << 16);
                hp |= (unsigned long long)hb                   << (16*e);
                lp |= (unsigned long long)bf16_rne(kx[e] - hf) << (16*e);
                qp |= (unsigned long long)bf16_rne(qx[e])      << (16*e);
            }
            int base = row * LDS_STRIDE + c*4;
            *(unsigned long long*)(khi + base) = hp;
            *(unsigned long long*)(klo + base) = lp;
            *(unsigned long long*)(qhi + base) = qp;
        }
    }
    __syncthreads();

    // ---- fused k-loop: accC = K·S^T (3-pass), accQ = Q·S^T (1-pass) ----
    f32x4 accC[4][2];
    f32x4 accQ[4][2];
#pragma unroll
    for (int ms = 0; ms < 4; ++ms)
#pragma unroll
        for (int ts = 0; ts < 2; ++ts){
            accC[ms][ts] = (f32x4){0.f,0.f,0.f,0.f};
            accQ[ms][ts] = (f32x4){0.f,0.f,0.f,0.f};
        }

#pragma unroll
    for (int ks = 0; ks < 4; ++ks){
        short8 ah[4], al[4];
        load_afrags<USE_TAB>(shi_tab, slo_tab, S, wave, ks, l16, quad, lane,
                             ah, al);
#pragma unroll
        for (int ts = 0; ts < 2; ++ts){
            const int off = (ts*16 + l16) * LDS_STRIDE + ks*32 + quad*8;
            short8 bk = *(const short8*)(khi + off);
            short8 bl = *(const short8*)(klo + off);
            short8 bq = *(const short8*)(qhi + off);
#pragma unroll
            for (int ms = 0; ms < 4; ++ms){
                accC[ms][ts] = __builtin_amdgcn_mfma_f32_16x16x32_bf16(ah[ms], bk, accC[ms][ts], 0,0,0);
                accC[ms][ts] = __builtin_amdgcn_mfma_f32_16x16x32_bf16(al[ms], bk, accC[ms][ts], 0,0,0);
                accC[ms][ts] = __builtin_amdgcn_mfma_f32_16x16x32_bf16(ah[ms], bl, accC[ms][ts], 0,0,0);
                accQ[ms][ts] = __builtin_amdgcn_mfma_f32_16x16x32_bf16(ah[ms], bq, accQ[ms][ts], 0,0,0);
            }
        }
    }

    // ---- epilogue: sign from accC (TAU-arbitered), apply to accQ ----
    // C/D layout: col(token)=lane&15, row(m)=quad*4+r
    float part0 = 0.f, part1 = 0.f;
#pragma unroll
    for (int ts = 0; ts < 2; ++ts){
#pragma unroll
        for (int ms = 0; ms < 4; ++ms){
#pragma unroll
            for (int r = 0; r < 4; ++r){
                float c = accC[ms][ts][r];
                float s = (c >= 0.f) ? 1.f : -1.f;
                if (__builtin_fabsf(c) < TAU)
                    s = ref_sign(Kg, S, tok0 + ts*16 + l16,
                                 wave*64 + ms*16 + quad*4 + r);
                float sv = s * accQ[ms][ts][r];   // s in {-1,0,1}: exact
                if (ts) part1 += sv; else part0 += sv;
            }
        }
    }

    // ---- reduce: token t in lanes {l16, l16+16, l16+32, l16+48} ----
    part0 += __shfl_xor(part0, 16, 64);
    part0 += __shfl_xor(part0, 32, 64);
    part1 += __shfl_xor(part1, 16, 64);
    part1 += __shfl_xor(part1, 32, 64);
    if (quad == 0){
        red[wave][l16]      = part0;
        red[wave][16 + l16] = part1;
    }
    __syncthreads();
    if (tid < TILE_T)
        out[tok0 + tid] = SCALE * (red[0][tid] + red[1][tid] + red[2][tid] + red[3][tid]);
}

extern "C" void kernel_launch(void* const* d_in, const int* in_sizes, int n_in,
                              void* d_out, int out_size, void* d_ws, size_t ws_size,
                              hipStream_t stream){
    const float* Qg = (const float*)d_in[0];
    const float* Kg = (const float*)d_in[1];
    const float* S  = (const float*)d_in[2];
    float* out = (float*)d_out;

    const size_t tab_elems = (size_t)NPROJ * DIM;        // 32768 per table
    const size_t need = 2 * tab_elems * sizeof(unsigned short);  // 128 KiB

    if (d_ws && ws_size >= need){
        unsigned short* shi = (unsigned short*)d_ws;
        unsigned short* slo = shi + tab_elems;
        prep_s_kernel<<<16, 256, 0, stream>>>(S, shi, slo);
        qjl_kernel<true><<<NWG, 256, 0, stream>>>(Qg, Kg, S, shi, slo, out);
    } else {
        qjl_kernel<false><<<NWG, 256, 0, stream>>>(Qg, Kg, S, nullptr, nullptr, out);
    }
}